// Round 6
// baseline (222.697 us; speedup 1.0000x reference)
//
#include <hip/hip_runtime.h>

// Least_Squares_weight: batched weighted 2-D Kabsch with GLOBAL weight sum.
// theta = atan2(H01-H10, H00+H11); t = G_B - R*G_A.
// Per-batch sums (12): s1=Σw, s2=Σw², sa=Σw·a, sb=Σw·b, ta=Σw²·a, tb=Σw²·b,
//   mp=Σw²·(a·b), mm=Σw²·(a×b)_z ;  G = sa/ws, ws = GLOBAL Σ s1.
//
// R6 = R5's k_partials (16-lane groups, depth-2 chunk pipeline, DPP reduce)
// + deterministic INTEGER-atomic global ws (2^38 fixed point, u64 atomicAdd:
// integer addition commutes exactly, so order doesn't matter) -> k_ws kernel
// and dense S1 array eliminated. ws accumulator zeroed via hipMemsetAsync.

#define NUMPTS 256
#define WS_SCALE 274877906944.0   // 2^38

// one DPP mov+add step; CTRL selects the xor distance (row-local, 16 lanes)
template <int CTRL>
__device__ __forceinline__ float dpp_add16(float v) {
    int x = __builtin_amdgcn_update_dpp(0, __float_as_int(v), CTRL, 0xF, 0xF, true);
    return v + __int_as_float(x);
}
// full 16-lane-group sum (every lane of the group ends with the group sum)
__device__ __forceinline__ float red16(float v) {
    v = dpp_add16<0xB1>(v);    // quad_perm [1,0,3,2]  (xor 1)
    v = dpp_add16<0x4E>(v);    // quad_perm [2,3,0,1]  (xor 2)
    v = dpp_add16<0x141>(v);   // row_half_mirror      (xor 4)
    v = dpp_add16<0x140>(v);   // row_mirror           (xor 8)
    return v;
}

// P record per batch (12 floats = 3 float4):
// 0:s2 1:sax 2:say 3:sbx | 4:sby 5:tax 6:tay 7:tbx | 8:tby 9:mp 10:mm 11:s1

// ---------------- kernel 1: per-batch partial sums ------------------------
__global__ __launch_bounds__(256) void k_partials(
    const float* __restrict__ A, const float* __restrict__ Bp,
    const float* __restrict__ W, float* __restrict__ P,
    unsigned long long* __restrict__ ws_acc, int Bn)
{
    const int lane = threadIdx.x & 63;
    const int wave = threadIdx.x >> 6;
    const int t = lane & 15;                        // sub-lane within group
    const int b = blockIdx.x * 16 + wave * 4 + (lane >> 4);

    const float4* A4 = (const float4*)(A + (size_t)b * (NUMPTS * 2));
    const float4* B4 = (const float4*)(Bp + (size_t)b * (NUMPTS * 2));
    const float4* W4 = (const float4*)(W + (size_t)b * NUMPTS);

    // double-buffered chunk pipeline: chunk j covers points 64j..64j+63
    // (per lane: 4 points = 2 A-float4 + 2 B-float4 + 1 W-float4)
    float4 a0[2], a1[2], b0[2], b1[2], wv[2];

    a0[0] = A4[2 * t];  a1[0] = A4[2 * t + 1];
    b0[0] = B4[2 * t];  b1[0] = B4[2 * t + 1];
    wv[0] = W4[t];

    float s1 = 0.f, s2 = 0.f, sax = 0.f, say = 0.f, sbx = 0.f, sby = 0.f;
    float tax = 0.f, tay = 0.f, tbx = 0.f, tby = 0.f;
    float mp = 0.f, mm = 0.f;

#define ACC(ax, ay, bx, by, w) do {                         \
        float _w = (w), _w2 = _w * _w;                      \
        s1 += _w;  s2 += _w2;                               \
        sax += _w * (ax);  say += _w * (ay);                \
        sbx += _w * (bx);  sby += _w * (by);                \
        tax += _w2 * (ax); tay += _w2 * (ay);               \
        tbx += _w2 * (bx); tby += _w2 * (by);               \
        mp += _w2 * ((ax) * (bx) + (ay) * (by));            \
        mm += _w2 * ((ax) * (by) - (ay) * (bx));            \
    } while (0)

#pragma unroll
    for (int j = 0; j < 4; ++j) {
        const int cur = j & 1;
        if (j < 3) {                                 // prefetch next chunk
            const int o = 32 * (j + 1);
            a0[cur ^ 1] = A4[2 * t + o];  a1[cur ^ 1] = A4[2 * t + o + 1];
            b0[cur ^ 1] = B4[2 * t + o];  b1[cur ^ 1] = B4[2 * t + o + 1];
            wv[cur ^ 1] = W4[t + 16 * (j + 1)];
        }
        const float4 ca0 = a0[cur], ca1 = a1[cur];
        const float4 cb0 = b0[cur], cb1 = b1[cur];
        const float4 cw  = wv[cur];
        ACC(ca0.x, ca0.y, cb0.x, cb0.y, cw.x);
        ACC(ca0.z, ca0.w, cb0.z, cb0.w, cw.y);
        ACC(ca1.x, ca1.y, cb1.x, cb1.y, cw.z);
        ACC(ca1.z, ca1.w, cb1.z, cb1.w, cw.w);
    }
#undef ACC

    // 16-lane-group reduction, once per wave: 4 DPP steps x 12 quantities
    s1  = red16(s1);   s2  = red16(s2);
    sax = red16(sax);  say = red16(say);
    sbx = red16(sbx);  sby = red16(sby);
    tax = red16(tax);  tay = red16(tay);
    tbx = red16(tbx);  tby = red16(tby);
    mp  = red16(mp);   mm  = red16(mm);

    if (t == 0) {
        float4* Pv = (float4*)P + (size_t)b * 3;
        Pv[0] = make_float4(s2,  sax, say, sbx);
        Pv[1] = make_float4(sby, tax, tay, tbx);
        Pv[2] = make_float4(tby, mp,  mm,  s1);
        // deterministic global ws: integer atomic add of 2^38 fixed-point s1
        // (s1 < 256, global ws < 2^24 -> max acc ~2^62, no overflow)
        atomicAdd(ws_acc, (unsigned long long)((double)s1 * WS_SCALE + 0.5));
    }
}

// ---------------- kernel 2: per-batch closed-form solve -------------------
__global__ __launch_bounds__(256) void k_final(
    const float* __restrict__ P,
    const unsigned long long* __restrict__ ws_acc,
    float* __restrict__ out, int Bn)
{
    const int b = blockIdx.x * 256 + threadIdx.x;
    if (b >= Bn) return;
    const size_t Bs = (size_t)Bn;

    const float4* Pv = (const float4*)P + (size_t)b * 3;
    const float4 p0 = Pv[0], p1 = Pv[1], p2 = Pv[2];

    const float s2  = p0.x;
    const float sax = p0.y, say = p0.z;
    const float sbx = p0.w, sby = p1.x;
    const float tax = p1.y, tay = p1.z;
    const float tbx = p1.w, tby = p2.x;
    const float mp  = p2.y, mm  = p2.z;

    const float ws  = (float)((double)ws_acc[0] * (1.0 / WS_SCALE));
    const float inv = 1.0f / ws;
    const float GAx = sax * inv, GAy = say * inv;
    const float GBx = sbx * inv, GBy = sby * inv;

    const float cp = mp - (tax * GBx + tay * GBy) - (GAx * tbx + GAy * tby)
                   + s2 * (GAx * GBx + GAy * GBy);
    const float sp = mm - (tax * GBy - tay * GBx) - (GAx * tby - GAy * tbx)
                   + s2 * (GAx * GBy - GAy * GBx);

    const float theta = atan2f(sp, cp);

    const float r = sqrtf(cp * cp + sp * sp);
    const float c = cp / r, s = sp / r;  // R = [[c,-s],[s,c]]

    const float tx = GBx - (c * GAx - s * GAy);
    const float ty = GBy - (s * GAx + c * GAy);

    out[0 * Bs + b] = theta;
    out[1 * Bs + b] = tx;
    out[2 * Bs + b] = ty;
}

// ---------------- launch ---------------------------------------------------
extern "C" void kernel_launch(void* const* d_in, const int* in_sizes, int n_in,
                              void* d_out, int out_size, void* d_ws, size_t ws_size,
                              hipStream_t stream) {
    const float* A  = (const float*)d_in[0];   // pstA  [B,256,2]
    const float* Bp = (const float*)d_in[1];   // pstB  [B,256,2]
    const float* W  = (const float*)d_in[2];   // weight[B,256,1]
    const int Bn = in_sizes[2] / NUMPTS;       // 65536

    float* P = (float*)d_ws;                   // [Bn][12] floats = 3 MiB
    unsigned long long* ws_acc =
        (unsigned long long*)(P + (size_t)Bn * 12);
    float* out = (float*)d_out;                // theta[Bn], tx[Bn], ty[Bn]

    hipMemsetAsync(ws_acc, 0, sizeof(unsigned long long), stream);
    hipLaunchKernelGGL(k_partials, dim3(Bn / 16), dim3(256), 0, stream,
                       A, Bp, W, P, ws_acc, Bn);
    hipLaunchKernelGGL(k_final, dim3(Bn / 256), dim3(256), 0, stream,
                       P, ws_acc, out, Bn);
}

// Round 7
// 62.440 us; speedup vs baseline: 3.5666x; 3.5666x over previous
//
#include <hip/hip_runtime.h>

// Least_Squares_weight: batched weighted 2-D Kabsch with GLOBAL weight sum.
// theta = atan2(H01-H10, H00+H11); t = G_B - R*G_A.
// Per-batch sums (12): s1=Σw, s2=Σw², sa=Σw·a, sb=Σw·b, ta=Σw²·a, tb=Σw²·b,
//   mp=Σw²·(a·b), mm=Σw²·(a×b)_z ;  G = sa/ws, ws = GLOBAL Σ s1.
//
// R7 = R5's k_partials (16-lane groups, depth-2 chunk pipeline, DPP reduce)
// + per-BLOCK s1 sums (LDS, fixed order -> deterministic, 4096 floats)
// + k_final redundantly reduces the 16KB BS1 array per block (identical
//   fixed-order tree in every block -> bit-identical ws, no extra kernel).
// R6's single-address u64 atomics (16K of them, one cacheline) serialized
// across XCDs: 219us. Never again.

#define NUMPTS 256

// one DPP mov+add step; CTRL selects the xor distance (row-local, 16 lanes)
template <int CTRL>
__device__ __forceinline__ float dpp_add16(float v) {
    int x = __builtin_amdgcn_update_dpp(0, __float_as_int(v), CTRL, 0xF, 0xF, true);
    return v + __int_as_float(x);
}
// full 16-lane-group sum (every lane of the group ends with the group sum)
__device__ __forceinline__ float red16(float v) {
    v = dpp_add16<0xB1>(v);    // quad_perm [1,0,3,2]  (xor 1)
    v = dpp_add16<0x4E>(v);    // quad_perm [2,3,0,1]  (xor 2)
    v = dpp_add16<0x141>(v);   // row_half_mirror      (xor 4)
    v = dpp_add16<0x140>(v);   // row_mirror           (xor 8)
    return v;
}

// P record per batch (12 floats = 3 float4):
// 0:s2 1:sax 2:say 3:sbx | 4:sby 5:tax 6:tay 7:tbx | 8:tby 9:mp 10:mm 11:s1

// ---------------- kernel 1: per-batch partial sums ------------------------
__global__ __launch_bounds__(256) void k_partials(
    const float* __restrict__ A, const float* __restrict__ Bp,
    const float* __restrict__ W, float* __restrict__ P,
    float* __restrict__ BS1, int Bn)
{
    const int lane = threadIdx.x & 63;
    const int wave = threadIdx.x >> 6;
    const int t = lane & 15;                        // sub-lane within group
    const int b = blockIdx.x * 16 + wave * 4 + (lane >> 4);

    const float4* A4 = (const float4*)(A + (size_t)b * (NUMPTS * 2));
    const float4* B4 = (const float4*)(Bp + (size_t)b * (NUMPTS * 2));
    const float4* W4 = (const float4*)(W + (size_t)b * NUMPTS);

    // double-buffered chunk pipeline: chunk j covers points 64j..64j+63
    // (per lane: 4 points = 2 A-float4 + 2 B-float4 + 1 W-float4)
    float4 a0[2], a1[2], b0[2], b1[2], wv[2];

    a0[0] = A4[2 * t];  a1[0] = A4[2 * t + 1];
    b0[0] = B4[2 * t];  b1[0] = B4[2 * t + 1];
    wv[0] = W4[t];

    float s1 = 0.f, s2 = 0.f, sax = 0.f, say = 0.f, sbx = 0.f, sby = 0.f;
    float tax = 0.f, tay = 0.f, tbx = 0.f, tby = 0.f;
    float mp = 0.f, mm = 0.f;

#define ACC(ax, ay, bx, by, w) do {                         \
        float _w = (w), _w2 = _w * _w;                      \
        s1 += _w;  s2 += _w2;                               \
        sax += _w * (ax);  say += _w * (ay);                \
        sbx += _w * (bx);  sby += _w * (by);                \
        tax += _w2 * (ax); tay += _w2 * (ay);               \
        tbx += _w2 * (bx); tby += _w2 * (by);               \
        mp += _w2 * ((ax) * (bx) + (ay) * (by));            \
        mm += _w2 * ((ax) * (by) - (ay) * (bx));            \
    } while (0)

#pragma unroll
    for (int j = 0; j < 4; ++j) {
        const int cur = j & 1;
        if (j < 3) {                                 // prefetch next chunk
            const int o = 32 * (j + 1);
            a0[cur ^ 1] = A4[2 * t + o];  a1[cur ^ 1] = A4[2 * t + o + 1];
            b0[cur ^ 1] = B4[2 * t + o];  b1[cur ^ 1] = B4[2 * t + o + 1];
            wv[cur ^ 1] = W4[t + 16 * (j + 1)];
        }
        const float4 ca0 = a0[cur], ca1 = a1[cur];
        const float4 cb0 = b0[cur], cb1 = b1[cur];
        const float4 cw  = wv[cur];
        ACC(ca0.x, ca0.y, cb0.x, cb0.y, cw.x);
        ACC(ca0.z, ca0.w, cb0.z, cb0.w, cw.y);
        ACC(ca1.x, ca1.y, cb1.x, cb1.y, cw.z);
        ACC(ca1.z, ca1.w, cb1.z, cb1.w, cw.w);
    }
#undef ACC

    // 16-lane-group reduction, once per wave: 4 DPP steps x 12 quantities
    s1  = red16(s1);   s2  = red16(s2);
    sax = red16(sax);  say = red16(say);
    sbx = red16(sbx);  sby = red16(sby);
    tax = red16(tax);  tay = red16(tay);
    tbx = red16(tbx);  tby = red16(tby);
    mp  = red16(mp);   mm  = red16(mm);

    __shared__ float sm[16];
    if (t == 0) {
        float4* Pv = (float4*)P + (size_t)b * 3;
        Pv[0] = make_float4(s2,  sax, say, sbx);
        Pv[1] = make_float4(sby, tax, tay, tbx);
        Pv[2] = make_float4(tby, mp,  mm,  s1);
        sm[wave * 4 + (lane >> 4)] = s1;             // 16 batch s1's
    }
    __syncthreads();
    if (threadIdx.x == 0) {                          // fixed-order block sum
        float v = 0.f;
#pragma unroll
        for (int i = 0; i < 16; ++i) v += sm[i];
        BS1[blockIdx.x] = v;
    }
}

// ---------------- kernel 2: redundant ws reduce + closed-form solve -------
__global__ __launch_bounds__(256) void k_final(
    const float* __restrict__ P, const float* __restrict__ BS1,
    float* __restrict__ out, int Bn)
{
    // ---- every block computes the SAME deterministic ws from BS1[4096] ---
    // thread i: fixed-order sum of BS1[16i .. 16i+15] (4x float4, L2-hot)
    const int tid = threadIdx.x;
    const float4* S4 = (const float4*)BS1;
    float acc = 0.f;
#pragma unroll
    for (int j = 0; j < 4; ++j) {
        float4 v = S4[tid * 4 + j];
        acc += ((v.x + v.y) + (v.z + v.w));
    }
    // deterministic butterfly within each wave (fixed sequence)
#pragma unroll
    for (int m = 32; m >= 1; m >>= 1) acc += __shfl_xor(acc, m);

    __shared__ float sm[4];
    __shared__ float ws_sh;
    if ((tid & 63) == 0) sm[tid >> 6] = acc;
    __syncthreads();
    if (tid == 0) ws_sh = ((sm[0] + sm[1]) + (sm[2] + sm[3]));
    __syncthreads();
    const float ws = ws_sh;

    // ---- per-batch closed-form solve -------------------------------------
    const int b = blockIdx.x * 256 + tid;
    const size_t Bs = (size_t)Bn;

    const float4* Pv = (const float4*)P + (size_t)b * 3;
    const float4 p0 = Pv[0], p1 = Pv[1], p2 = Pv[2];

    const float s2  = p0.x;
    const float sax = p0.y, say = p0.z;
    const float sbx = p0.w, sby = p1.x;
    const float tax = p1.y, tay = p1.z;
    const float tbx = p1.w, tby = p2.x;
    const float mp  = p2.y, mm  = p2.z;

    const float inv = 1.0f / ws;
    const float GAx = sax * inv, GAy = say * inv;
    const float GBx = sbx * inv, GBy = sby * inv;

    const float cp = mp - (tax * GBx + tay * GBy) - (GAx * tbx + GAy * tby)
                   + s2 * (GAx * GBx + GAy * GBy);
    const float sp = mm - (tax * GBy - tay * GBx) - (GAx * tby - GAy * tbx)
                   + s2 * (GAx * GBy - GAy * GBx);

    const float theta = atan2f(sp, cp);

    const float r = sqrtf(cp * cp + sp * sp);
    const float c = cp / r, s = sp / r;  // R = [[c,-s],[s,c]]

    const float tx = GBx - (c * GAx - s * GAy);
    const float ty = GBy - (s * GAx + c * GAy);

    out[0 * Bs + b] = theta;
    out[1 * Bs + b] = tx;
    out[2 * Bs + b] = ty;
}

// ---------------- launch ---------------------------------------------------
extern "C" void kernel_launch(void* const* d_in, const int* in_sizes, int n_in,
                              void* d_out, int out_size, void* d_ws, size_t ws_size,
                              hipStream_t stream) {
    const float* A  = (const float*)d_in[0];   // pstA  [B,256,2]
    const float* Bp = (const float*)d_in[1];   // pstB  [B,256,2]
    const float* W  = (const float*)d_in[2];   // weight[B,256,1]
    const int Bn = in_sizes[2] / NUMPTS;       // 65536

    float* P   = (float*)d_ws;                 // [Bn][12] floats = 3 MiB
    float* BS1 = P + (size_t)Bn * 12;          // per-block s1 sums, 16 KB
    float* out = (float*)d_out;                // theta[Bn], tx[Bn], ty[Bn]

    hipLaunchKernelGGL(k_partials, dim3(Bn / 16), dim3(256), 0, stream,
                       A, Bp, W, P, BS1, Bn);
    hipLaunchKernelGGL(k_final, dim3(Bn / 256), dim3(256), 0, stream,
                       P, BS1, out, Bn);
}